// Round 2
// baseline (2116.058 us; speedup 1.0000x reference)
//
#include <hip/hip_runtime.h>

// WKV7 recurrence, T=4096, H=32, N=64, fp32.
// Key fact: the H*N = 2048 state ROWS evolve independently:
//   sa[i]    = dot(s[i,:], a_t)
//   s[i,j]   = s[i,j]*w_t[j] + sa[i]*b_t[j] + v_t[i]*k_t[j]
//   x_t[i]   = dot(s[i,:], r_t)          (post-update state)
// -> one wave per row (lane j holds s[i][j]); 2048 waves = 8 waves/CU on 256 CUs.

static constexpr int T_LEN = 4096;
static constexpr int H_HEADS = 32;
static constexpr int N_DIM = 64;
static constexpr int HN = H_HEADS * N_DIM;                 // 2048
static constexpr int WAVES_PER_BLOCK = 8;                  // rows per block
static constexpr int BLOCK_THREADS = WAVES_PER_BLOCK * 64; // 512
static constexpr int NUM_BLOCKS = (H_HEADS * N_DIM) / WAVES_PER_BLOCK; // 256

// x += dpp_move(x); masked-out / out-of-range lanes contribute 0 (old=0).
template <int CTRL, int RM>
__device__ __forceinline__ float dpp_add(float x) {
  int m = __builtin_amdgcn_update_dpp(0, __float_as_int(x), CTRL, RM, 0xf, false);
  return x + __int_as_float(m);
}

// Canonical GCN 64-lane sum: row_shr 1,2,4,8 then row_bcast15 (rows 1,3),
// row_bcast31 (rows 2,3); total lands in lane 63; broadcast via readlane.
__device__ __forceinline__ float wave_sum_bcast(float x) {
  x = dpp_add<0x111, 0xf>(x); // row_shr:1
  x = dpp_add<0x112, 0xf>(x); // row_shr:2
  x = dpp_add<0x114, 0xf>(x); // row_shr:4
  x = dpp_add<0x118, 0xf>(x); // row_shr:8
  x = dpp_add<0x142, 0xa>(x); // row_bcast:15 -> rows 1,3
  x = dpp_add<0x143, 0xc>(x); // row_bcast:31 -> rows 2,3
  return __int_as_float(__builtin_amdgcn_readlane(__float_as_int(x), 63));
}

__global__ __launch_bounds__(BLOCK_THREADS, 2) void wkv7_scan(
    const float* __restrict__ rp, const float* __restrict__ wp,
    const float* __restrict__ kp, const float* __restrict__ vp,
    const float* __restrict__ ap, const float* __restrict__ bp,
    const float* __restrict__ s0p, float* __restrict__ xp,
    float* __restrict__ sop) {
  const int tid  = threadIdx.x;
  const int lane = tid & 63;
  const int wv   = tid >> 6;
  const int blk  = blockIdx.x;
  // head = blk % 32 so the 8 blocks of a head are {h, h+32, ...}: all equal
  // mod 8 -> same XCD under round-robin dispatch (L2 reuse of head vectors).
  const int h     = blk & (H_HEADS - 1);
  const int ibase = (blk >> 5) * WAVES_PER_BLOCK;
  const int i     = ibase + wv;      // row 0..63 within head
  const int hb    = h * N_DIM;

  __shared__ float xbuf[WAVES_PER_BLOCK][65]; // +1 pad

  // state row: lane j holds s[i][j]
  float s = s0p[(size_t)(hb + i) * N_DIM + lane];

  int off = hb + lane;                                      // [t=0, h*64+j]
  const int vbase = __builtin_amdgcn_readfirstlane(hb + i); // force s_load path
  int vo = vbase;

  // software pipeline: current regs + prefetch next step
  float wc = wp[off], ac = ap[off], bc = bp[off], kc = kp[off], rc = rp[off];
  float vc = vp[vo];
  float xacc = 0.0f;

  for (int t = 0; t < T_LEN; ++t) {
    const int step = (t < T_LEN - 1) ? HN : 0; // clamp: no OOB on last iter
    const int noff = off + step;
    const int nvo  = vo + step;
    const float wn = wp[noff], an = ap[noff], bn = bp[noff],
                kn = kp[noff], rn = rp[noff];
    const float vn = vp[nvo];

    // sa from PRE-update state
    const float sa = wave_sum_bcast(s * ac);
    // s = s*w + sa*b + v*k   (sa, vc are wave-uniform -> SGPR operands)
    s = fmaf(s, wc, fmaf(sa, bc, vc * kc));
    // x_t from POST-update state
    const float xv = wave_sum_bcast(s * rc);
    // stash x_t into lane (t%64) of the rotating accumulator:
    // v_cmp_eq + v_cndmask (xv is wave-uniform; no writelane builtin on this clang)
    xacc = (lane == (t & 63)) ? xv : xacc;

    if ((t & 63) == 63) {
      // transpose through LDS -> coalesced 32B-contiguous stores
      xbuf[wv][lane] = xacc;
      __syncthreads();
      const int tl = tid >> 3; // local t 0..63
      const int iw = tid & 7;  // which row of the block
      const int t0 = t - 63;
      xp[(size_t)(t0 + tl) * HN + hb + ibase + iw] = xbuf[iw][tl];
      __syncthreads();
    }

    wc = wn; ac = an; bc = bn; kc = kn; rc = rn; vc = vn;
    off = noff; vo = nvo;
  }

  // final state2_out [H,N,N]
  sop[(size_t)(hb + i) * N_DIM + lane] = s;
}

extern "C" void kernel_launch(void* const* d_in, const int* in_sizes, int n_in,
                              void* d_out, int out_size, void* d_ws, size_t ws_size,
                              hipStream_t stream) {
  // setup_inputs order: seq_length(int,1), r, w, k, v, a, b, state2
  const float* r  = (const float*)d_in[1];
  const float* w  = (const float*)d_in[2];
  const float* k  = (const float*)d_in[3];
  const float* v  = (const float*)d_in[4];
  const float* a  = (const float*)d_in[5];
  const float* b  = (const float*)d_in[6];
  const float* s0 = (const float*)d_in[7];
  float* x    = (float*)d_out;                       // [T,H,1,N] flat
  float* sout = x + (size_t)T_LEN * H_HEADS * N_DIM; // [H,N,N]

  wkv7_scan<<<dim3(NUM_BLOCKS), dim3(BLOCK_THREADS), 0, stream>>>(
      r, w, k, v, a, b, s0, x, sout);
}

// Round 3
// 833.715 us; speedup vs baseline: 2.5381x; 2.5381x over previous
//
#include <hip/hip_runtime.h>

// WKV7 recurrence, T=4096, H=32, N=64, fp32.
// One wave per state row i of head h (lane j holds s[i][j]); 2048 waves total
// = 8 waves/CU (structural occupancy limit). R2 post-mortem: latency-bound at
// ~1166 cy/step (1-step prefetch vs ~900 cy HBM latency). This version uses an
// 8-step register double-buffered chunk: 48 loads in flight a full chunk ahead.

static constexpr int T_LEN = 4096;
static constexpr int H_HEADS = 32;
static constexpr int N_DIM = 64;
static constexpr int HN = H_HEADS * N_DIM;                 // 2048
static constexpr int WAVES_PER_BLOCK = 8;
static constexpr int BLOCK_THREADS = WAVES_PER_BLOCK * 64; // 512
static constexpr int NUM_BLOCKS = (H_HEADS * N_DIM) / WAVES_PER_BLOCK; // 256
static constexpr int C = 8;                                // chunk (steps)
static constexpr int TC = T_LEN / C;                       // 512 chunks

template <int CTRL, int RM>
__device__ __forceinline__ float dpp_add(float x) {
  int m = __builtin_amdgcn_update_dpp(0, __float_as_int(x), CTRL, RM, 0xf, false);
  return x + __int_as_float(m);
}

// 64-lane sum -> broadcast (row_shr 1,2,4,8; row_bcast15; row_bcast31; readlane 63)
__device__ __forceinline__ float wave_sum_bcast(float x) {
  x = dpp_add<0x111, 0xf>(x);
  x = dpp_add<0x112, 0xf>(x);
  x = dpp_add<0x114, 0xf>(x);
  x = dpp_add<0x118, 0xf>(x);
  x = dpp_add<0x142, 0xa>(x);
  x = dpp_add<0x143, 0xc>(x);
  return __int_as_float(__builtin_amdgcn_readlane(__float_as_int(x), 63));
}

__global__ __launch_bounds__(BLOCK_THREADS, 2) void wkv7_scan(
    const float* __restrict__ rp, const float* __restrict__ wp,
    const float* __restrict__ kp, const float* __restrict__ vp,
    const float* __restrict__ ap, const float* __restrict__ bp,
    const float* __restrict__ s0p, float* __restrict__ xp,
    float* __restrict__ sop) {
  const int tid  = threadIdx.x;
  const int lane = tid & 63;
  const int wv   = tid >> 6;
  const int blk  = blockIdx.x;
  const int h     = blk & (H_HEADS - 1);           // 8 blocks/head spread over XCDs
  const int ibase = (blk >> 5) * WAVES_PER_BLOCK;
  const int i     = ibase + wv;
  const int hb    = h * N_DIM;

  __shared__ float xbuf[WAVES_PER_BLOCK][65];

  float s = s0p[(size_t)(hb + i) * N_DIM + lane];

  const int base_vl = hb + lane; // coalesced 256B wave-load offset
  const int base_vu = hb + i;    // wave-uniform (v broadcast load)

  // double-buffered chunk registers: 6 arrays x 8 steps x 2 bufs = 96 VGPRs
  float wb[2][C], ab_[2][C], bb[2][C], kb[2][C], rb[2][C], vb[2][C];
  float xacc = 0.0f;

#define LOAD_CHUNK(CI, BI)                                          \
  do {                                                              \
    const int cc = (CI) < TC - 1 ? (CI) : TC - 1;                   \
    const int cb = cc * (C * HN);                                   \
    _Pragma("unroll")                                               \
    for (int u = 0; u < C; ++u) {                                   \
      const int o = cb + u * HN + base_vl;                          \
      wb[BI][u] = wp[o];                                            \
      ab_[BI][u] = ap[o];                                           \
      bb[BI][u] = bp[o];                                            \
      kb[BI][u] = kp[o];                                            \
      rb[BI][u] = rp[o];                                            \
      vb[BI][u] = vp[cb + u * HN + base_vu];                        \
    }                                                               \
  } while (0)

#define COMPUTE_CHUNK(CI, BI)                                               \
  do {                                                                      \
    _Pragma("unroll")                                                       \
    for (int u = 0; u < C; ++u) {                                           \
      const float sa = wave_sum_bcast(s * ab_[BI][u]);                      \
      s = fmaf(s, wb[BI][u], fmaf(sa, bb[BI][u], vb[BI][u] * kb[BI][u]));   \
      const float xv = wave_sum_bcast(s * rb[BI][u]);                       \
      const int tl = (((CI) & 7) << 3) | u;                                 \
      xacc = (lane == tl) ? xv : xacc;                                      \
    }                                                                       \
  } while (0)

  LOAD_CHUNK(0, 0);

  for (int c = 0; c < TC; c += 2) {
    LOAD_CHUNK(c + 1, 1);
    COMPUTE_CHUNK(c, 0);
    LOAD_CHUNK(c + 2, 0);
    COMPUTE_CHUNK(c + 1, 1);

    if ((c & 7) == 6) {
      // 64 steps complete: transpose through LDS -> coalesced stores
      xbuf[wv][lane] = xacc;
      __syncthreads();
      const int tl2 = tid >> 3;
      const int iw  = tid & 7;
      const int t0  = (c + 2) * C - 64;
      xp[(size_t)(t0 + tl2) * HN + hb + ibase + iw] = xbuf[iw][tl2];
      __syncthreads();
    }
  }

#undef LOAD_CHUNK
#undef COMPUTE_CHUNK

  sop[(size_t)(hb + i) * N_DIM + lane] = s;
}

extern "C" void kernel_launch(void* const* d_in, const int* in_sizes, int n_in,
                              void* d_out, int out_size, void* d_ws, size_t ws_size,
                              hipStream_t stream) {
  // setup_inputs order: seq_length(int,1), r, w, k, v, a, b, state2
  const float* r  = (const float*)d_in[1];
  const float* w  = (const float*)d_in[2];
  const float* k  = (const float*)d_in[3];
  const float* v  = (const float*)d_in[4];
  const float* a  = (const float*)d_in[5];
  const float* b  = (const float*)d_in[6];
  const float* s0 = (const float*)d_in[7];
  float* x    = (float*)d_out;                       // [T,H,1,N] flat
  float* sout = x + (size_t)T_LEN * H_HEADS * N_DIM; // [H,N,N]

  wkv7_scan<<<dim3(NUM_BLOCKS), dim3(BLOCK_THREADS), 0, stream>>>(
      r, w, k, v, a, b, s0, x, sout);
}